// Round 6
// baseline (379.850 us; speedup 1.0000x reference)
//
#include <hip/hip_runtime.h>
#include <stdint.h>

#define DIM 2048

typedef short short8 __attribute__((ext_vector_type(8)));
typedef float f32x4 __attribute__((ext_vector_type(4)));
typedef float f32x16 __attribute__((ext_vector_type(16)));

__device__ __forceinline__ unsigned short f2bf(float f) {
    union { float f; unsigned int u; } v;
    v.f = f;
    unsigned int r = v.u + 0x7FFFu + ((v.u >> 16) & 1u);  // round-to-nearest-even
    return (unsigned short)(r >> 16);
}
__device__ __forceinline__ float bf2f(unsigned short u) {
    union { unsigned int u; float f; } v;
    v.u = ((unsigned int)u) << 16;
    return v.f;
}

// async global->LDS, 16B per lane. LDS dest must be wave-uniform base + lane*16.
__device__ __forceinline__ void async16(const unsigned short* g, unsigned short* l) {
    __builtin_amdgcn_global_load_lds(
        (__attribute__((address_space(1))) void*)(uintptr_t)g,
        (__attribute__((address_space(3))) void*)(uintptr_t)l,
        16, 0, 0);
}

// Tiled skew-symmetric build: one block per upper-tri 64x64 tile pair.
__global__ __launch_bounds__(256) void build_A_tiled(const float* __restrict__ ang,
                                                     unsigned short* __restrict__ A) {
    __shared__ float tile[64][65];
    int b = blockIdx.x;
    int ti = 0, rem = b;
    while (rem >= 32 - ti) { rem -= 32 - ti; ++ti; }
    const int tj = ti + rem;
    const int t  = threadIdx.x;
    const int lj = t & 63;
    const int lw = t >> 6;
    const bool diag = (ti == tj);

#pragma unroll
    for (int m = 0; m < 16; ++m) {
        const int li = lw * 16 + m;
        const int i = ti * 64 + li;
        const int j = tj * 64 + lj;
        float v = 0.0f;
        if (i < j) v = ang[i * (4095 - i) / 2 + (j - i - 1)];
        tile[li][lj] = v;
    }
    __syncthreads();

#pragma unroll
    for (int m = 0; m < 16; ++m) {
        const int li = lw * 16 + m;
        float v;
        if (diag) {
            if (li < lj)      v =  tile[li][lj];
            else if (li > lj) v = -tile[lj][li];
            else              v = 0.0f;
        } else {
            v = tile[li][lj];
        }
        A[(size_t)(ti * 64 + li) * DIM + tj * 64 + lj] = f2bf(v);
    }
    if (!diag) {
#pragma unroll
        for (int m = 0; m < 16; ++m) {
            const int li = lw * 16 + m;
            A[(size_t)(tj * 64 + li) * DIM + ti * 64 + lj] = f2bf(-tile[lj][li]);
        }
    }
}

// ---------------------------------------------------------------------------
// Merged Wt-builder + x-conversion. Blocks [0,512): Wt = I - 2A - A*A^T
// (128x64 tiles, 16:12 MFMA:ds_read, XCD swizzle). Blocks [512, 512+32768):
// fp32->bf16 cvt of x. The two are dependency-independent; s64 blocks are
// compute-bound (MFMA pipe), cvt blocks memory-bound (HBM pipe) -> they
// overlap (m114: co-scheduled MFMA/mem waves ~ max, not sum). s64 first so
// its 512 blocks grab CUs immediately; cvt backfills.
// ---------------------------------------------------------------------------
__global__ __launch_bounds__(256) void s64_cvt(
        const unsigned short* __restrict__ A,
        unsigned short* __restrict__ Wt,
        const float* __restrict__ x,
        unsigned short* __restrict__ xbf) {
    __shared__ __align__(16) unsigned short ldsA[128 * 64];  // 16 KB
    __shared__ __align__(16) unsigned short ldsB[64 * 64];   //  8 KB

    if (blockIdx.x >= 512) {
        // fp32 -> bf16, 4 elems/thread
        const int i = ((blockIdx.x - 512) * 256 + threadIdx.x) * 4;
        const float4 v = *(const float4*)(x + i);
        ushort4 o;
        o.x = f2bf(v.x); o.y = f2bf(v.y); o.z = f2bf(v.z); o.w = f2bf(v.w);
        *(ushort4*)(xbf + i) = o;
        return;
    }

    const int K = DIM, N = DIM;
    const int t    = threadIdx.x;
    const int flat = blockIdx.x;                             // 0..511
    const int swz  = (flat & 7) * 64 + (flat >> 3);          // bijective
    const int bn   = (swz & 31) * 64;
    const int bm   = (swz >> 5) * 128;
    const int lane = t & 63;
    const int wave = t >> 6;
    const int waveM = (wave >> 1) * 64;
    const int waveN = (wave & 1) * 32;
    const int fm = lane & 15;
    const int fq = lane >> 4;

    f32x4 acc[4][2];
#pragma unroll
    for (int i = 0; i < 4; ++i)
#pragma unroll
        for (int j = 0; j < 2; ++j)
            acc[i][j] = (f32x4){0.f, 0.f, 0.f, 0.f};

    const int trow   = t >> 3;                  // 0..31
    const int tchunk = (t & 7) ^ (trow & 7);    // swizzled source k-chunk
    const unsigned short* gA = A + (size_t)(bm + trow) * K + tchunk * 8;
    const unsigned short* gB = A + (size_t)(bn + trow) * K + tchunk * 8;
    const size_t rowskip = (size_t)32 * K;
    unsigned short* lA = ldsA + t * 8;
    unsigned short* lB = ldsB + t * 8;

    for (int kt = 0; kt < K; kt += 64) {
        __syncthreads();
        async16(gA + kt,                lA);
        async16(gA + kt +     rowskip,  lA + 2048);
        async16(gA + kt + 2 * rowskip,  lA + 4096);
        async16(gA + kt + 3 * rowskip,  lA + 6144);
        async16(gB + kt,                lB);
        async16(gB + kt +     rowskip,  lB + 2048);
        __syncthreads();

#pragma unroll
        for (int ks = 0; ks < 2; ++ks) {
            short8 af[4], bfv[2];
#pragma unroll
            for (int i = 0; i < 4; ++i) {
                const int rowA = waveM + i * 16 + fm;
                af[i] = *(const short8*)(ldsA + rowA * 64 + (((ks << 2) + fq) ^ (rowA & 7)) * 8);
            }
#pragma unroll
            for (int j = 0; j < 2; ++j) {
                const int rowB = waveN + j * 16 + fm;
                bfv[j] = *(const short8*)(ldsB + rowB * 64 + (((ks << 2) + fq) ^ (rowB & 7)) * 8);
            }
#pragma unroll
            for (int i = 0; i < 4; ++i)
#pragma unroll
                for (int j = 0; j < 2; ++j)
                    acc[i][j] = __builtin_amdgcn_mfma_f32_16x16x32_bf16(
                        af[i], bfv[j], acc[i][j], 0, 0, 0);
        }
    }

#pragma unroll
    for (int i = 0; i < 4; ++i) {
#pragma unroll
        for (int j = 0; j < 2; ++j) {
            const int col = bn + waveN + j * 16 + fm;
#pragma unroll
            for (int r = 0; r < 4; ++r) {
                const int row = bm + waveM + i * 16 + fq * 4 + r;
                const float a = bf2f(A[(size_t)row * N + col]);
                const float w = (row == col ? 1.0f : 0.0f) - 2.0f * a - acc[i][j][r];
                Wt[(size_t)row * N + col] = f2bf(w);
            }
        }
    }
}

// ---------------------------------------------------------------------------
// Main NT GEMM, 256x256 tile, BK=64, balanced 4-phase counted-vmcnt pipeline,
// now on v_mfma_f32_32x32x16_bf16 (4060 FLOP/cyc/CU vs 3378 for 16x16x32,
// m119/m06; per-CU matrix-issue per K-tile 2066 vs 2483 cyc). LDS traffic,
// staging, swizzle, barriers, vmcnt placement all unchanged from the
// 120us/48%-MfmaUtil/0-conflict version. Per wave: 4x2 tiles of 32x32,
// acc[4][2] f32x16 (128 VGPR). C-map: col=lane&31,
// row=(reg&3)+8*(reg>>2)+4*(lane>>5)  [HW-verified m74/m101].
// ---------------------------------------------------------------------------

#define WAITV(N) asm volatile("s_waitcnt vmcnt(" #N ")" ::: "memory")
#define BAR() do { asm volatile("" ::: "memory"); __builtin_amdgcn_s_barrier(); asm volatile("" ::: "memory"); } while (0)

#define STG_A(BUF, R0, KT) async16(gA + (size_t)(R0) * 2048 + (KT), &ldsA[BUF][(R0) * 64 + t * 8])
#define STG_B(BUF, R0, KT) async16(gB + (size_t)(R0) * 2048 + (KT), &ldsB[BUF][(R0) * 64 + t * 8])

// A fragments for i-half IH into af (8x ds_read_b128): 2 m-tiles x 4 k-steps
#define READ_A_(BUF, IH) do { \
    _Pragma("unroll") \
    for (int ii = 0; ii < 2; ++ii) { \
        const int row  = waveM + ((IH) * 2 + ii) * 32 + r32; \
        const int base = row * 64; \
        _Pragma("unroll") \
        for (int ks = 0; ks < 4; ++ks) \
            af[ii][ks] = *(const short8*)(&ldsA[BUF][base + (((ks << 1) + hi) ^ (row & 7)) * 8]); \
    } } while (0)

// B fragments for j-half JH into bfr[JH] (4x ds_read_b128): 1 n-tile x 4 k-steps
#define READ_B_(BUF, JH) do { \
    { \
        const int row  = (JH) * 128 + wn * 32 + r32; \
        const int base = row * 64; \
        _Pragma("unroll") \
        for (int ks = 0; ks < 4; ++ks) \
            bfr[JH][ks] = *(const short8*)(&ldsB[BUF][base + (((ks << 1) + hi) ^ (row & 7)) * 8]); \
    } } while (0)

#define MMAQ(IH, JH) do { \
    __builtin_amdgcn_s_setprio(1); \
    _Pragma("unroll") \
    for (int ks = 0; ks < 4; ++ks) \
    _Pragma("unroll") \
    for (int ii = 0; ii < 2; ++ii) \
        acc[(IH) * 2 + ii][JH] = __builtin_amdgcn_mfma_f32_32x32x16_bf16( \
            af[ii][ks], bfr[JH][ks], acc[(IH) * 2 + ii][JH], 0, 0, 0); \
    __builtin_amdgcn_s_setprio(0); \
} while (0)

// One K-tile. PRE: prefetch tile T+2 (k-elem KTN) into same buffer.
// VN: vmcnt arg at P3 (6 steady; 0 for tile 30). NXT: pre-read tile T+1 frags.
#define TILE(BUF, KTN, PRE, VN, NXT) do { \
    /* P1: quads (0..1, 0) */ \
    BAR(); \
    if (PRE) { STG_A(BUF, 0, KTN); STG_A(BUF, 128, KTN); STG_B(BUF, 0, KTN); STG_B(BUF, 64, KTN); } \
    MMAQ(0, 0); \
    READ_B_(BUF, 1); \
    /* P2: quads (0..1, 1) */ \
    BAR(); \
    if (PRE) { STG_B(BUF, 128, KTN); STG_B(BUF, 192, KTN); } \
    MMAQ(0, 1); \
    READ_A_(BUF, 1); \
    /* P3: quads (2..3, 0) */ \
    WAITV(VN); \
    BAR(); \
    if (PRE) { STG_A(BUF, 64, KTN); STG_A(BUF, 192, KTN); } \
    MMAQ(1, 0); \
    if (NXT) READ_B_((BUF) ^ 1, 0); \
    /* P4: quads (2..3, 1) */ \
    BAR(); \
    MMAQ(1, 1); \
    if (NXT) READ_A_((BUF) ^ 1, 0); \
} while (0)

#define TILE_LAST(BUF) do { \
    BAR(); MMAQ(0, 0); READ_B_(BUF, 1); \
    BAR(); MMAQ(0, 1); READ_A_(BUF, 1); \
    BAR(); MMAQ(1, 0); \
    MMAQ(1, 1); \
} while (0)

__global__ __launch_bounds__(512, 2) void gemm_main(
        const unsigned short* __restrict__ Aop,   // x bf16 [M][K]
        const unsigned short* __restrict__ Bop,   // Wt bf16 [N][K]
        int M, int N, int K,
        const float* __restrict__ bias,
        float* __restrict__ out) {
    __shared__ __align__(16) unsigned short ldsA[2][256 * 64];  // 2 x 32 KB
    __shared__ __align__(16) unsigned short ldsB[2][256 * 64];  // 2 x 32 KB

    const int t    = threadIdx.x;
    // XCD-aware bijective swizzle over the 8x64 grid (512 blocks, 512%8==0).
    const int flat = blockIdx.y * 8 + blockIdx.x;
    const int swz  = (flat & 7) * 64 + (flat >> 3);
    const int bn   = (swz & 7) * 256;
    const int bm   = (swz >> 3) * 256;
    const int lane = t & 63;
    const int wave = t >> 6;        // 0..7
    const int wm   = wave >> 2;     // 0..1
    const int wn   = wave & 3;      // 0..3
    const int waveM = wm * 128;
    const int r32  = lane & 31;     // 32x32 fragment row/col
    const int hi   = lane >> 5;     // k-subchunk select

    f32x16 acc[4][2];
#pragma unroll
    for (int i = 0; i < 4; ++i)
#pragma unroll
        for (int j = 0; j < 2; ++j)
#pragma unroll
            for (int r = 0; r < 16; ++r)
                acc[i][j][r] = 0.f;

    short8 af[2][4];        // A frags, current i-half (2 m-tiles x 4 ks)
    short8 bfr[2][4];       // B frags per j-half (1 n-tile x 4 ks)

    const int trow   = t >> 3;                  // 0..63
    const int tchunk = (t & 7) ^ (trow & 7);    // pre-swizzled source k-chunk
    const unsigned short* gA = Aop + (size_t)(bm + trow) * 2048 + tchunk * 8;
    const unsigned short* gB = Bop + (size_t)(bn + trow) * 2048 + tchunk * 8;

    // Prologue: stage tile 0 -> buf0 (8 oldest), tile 1 -> buf1.
    STG_A(0, 0, 0);   STG_A(0, 128, 0);  STG_B(0, 0, 0);   STG_B(0, 64, 0);
    STG_B(0, 128, 0); STG_B(0, 192, 0);  STG_A(0, 64, 0);  STG_A(0, 192, 0);
    STG_A(1, 0, 64);  STG_A(1, 128, 64); STG_B(1, 0, 64);  STG_B(1, 64, 64);
    STG_B(1, 128, 64);STG_B(1, 192, 64); STG_A(1, 64, 64); STG_A(1, 192, 64);
    WAITV(8);           // tile 0's 8 retired; tile 1's 8 in flight
    BAR();
    READ_A_(0, 0);      // af   = A0(tile 0)
    READ_B_(0, 0);      // bfr0 = B0(tile 0)

    // Main loop: tiles 0..29, full prefetch of tiles 2..31.
#pragma unroll 1
    for (int it = 0; it < 15; ++it) {
        const int kt = it * 128;
        TILE(0, kt + 128, 1, 6, 1);   // tile 2it,   prefetch 2it+2
        TILE(1, kt + 192, 1, 6, 1);   // tile 2it+1, prefetch 2it+3
    }
    // Tail: tile 30 (wait out tile 31's loads at P3), tile 31.
    TILE(0, 0, 0, 0, 1);
    TILE_LAST(1);

    // Epilogue: acc -> out (+bias). 32x32 C-map: col=lane&31,
    // row=(reg&3)+8*(reg>>2)+4*(lane>>5). j-half JH covers cols JH*128+wn*32.
#pragma unroll
    for (int i = 0; i < 4; ++i) {
        const int rowb = bm + waveM + i * 32 + 4 * hi;
#pragma unroll
        for (int j = 0; j < 2; ++j) {
            const int col = bn + j * 128 + wn * 32 + r32;
            const float b = bias[col];
#pragma unroll
            for (int r = 0; r < 16; ++r) {
                const int row = rowb + (r & 3) + 8 * (r >> 2);
                out[(size_t)row * 2048 + col] = acc[i][j][r] + b;
            }
        }
    }
}

extern "C" void kernel_launch(void* const* d_in, const int* in_sizes, int n_in,
                              void* d_out, int out_size, void* d_ws, size_t ws_size,
                              hipStream_t stream) {
    const float* x      = (const float*)d_in[0];   // 4*4096*2048
    const float* angles = (const float*)d_in[1];   // 2096128
    const float* bias   = (const float*)d_in[2];   // 2048
    float* out = (float*)d_out;

    char* ws = (char*)d_ws;
    unsigned short* Abf = (unsigned short*)ws;                      //  8 MB: A bf16
    unsigned short* Wt  = (unsigned short*)(ws + (8u << 20));       //  8 MB: W^T bf16
    unsigned short* xbf = (unsigned short*)(ws + (16u << 20));      // 64 MB: x bf16

    const int M = 4 * 4096;

    // build A (tiny, dependency of s64)
    build_A_tiled<<<528, 256, 0, stream>>>(angles, Abf);

    // Wt = I - 2A - A*A^T (512 blocks) overlapped with x fp32->bf16 (32768)
    s64_cvt<<<512 + 32768, 256, 0, stream>>>(Abf, Wt, x, xbf);

    // out = x @ W + bias via NT against Wt (16384 x 2048 x 2048)
    gemm_main<<<dim3(DIM / 256, M / 256), 512, 0, stream>>>(
        xbf, Wt, M, DIM, DIM, bias, out);
}

// Round 8
// 361.405 us; speedup vs baseline: 1.0510x; 1.0510x over previous
//
#include <hip/hip_runtime.h>
#include <stdint.h>

#define DIM 2048

typedef short short8 __attribute__((ext_vector_type(8)));
typedef float f32x4 __attribute__((ext_vector_type(4)));

__device__ __forceinline__ unsigned short f2bf(float f) {
    union { float f; unsigned int u; } v;
    v.f = f;
    unsigned int r = v.u + 0x7FFFu + ((v.u >> 16) & 1u);  // round-to-nearest-even
    return (unsigned short)(r >> 16);
}
__device__ __forceinline__ float bf2f(unsigned short u) {
    union { unsigned int u; float f; } v;
    v.u = ((unsigned int)u) << 16;
    return v.f;
}

// async global->LDS, 16B per lane. LDS dest must be wave-uniform base + lane*16.
__device__ __forceinline__ void async16(const unsigned short* g, unsigned short* l) {
    __builtin_amdgcn_global_load_lds(
        (__attribute__((address_space(1))) void*)(uintptr_t)g,
        (__attribute__((address_space(3))) void*)(uintptr_t)l,
        16, 0, 0);
}

// Tiled skew-symmetric build: one block per upper-tri 64x64 tile pair.
__global__ __launch_bounds__(256) void build_A_tiled(const float* __restrict__ ang,
                                                     unsigned short* __restrict__ A) {
    __shared__ float tile[64][65];
    int b = blockIdx.x;
    int ti = 0, rem = b;
    while (rem >= 32 - ti) { rem -= 32 - ti; ++ti; }
    const int tj = ti + rem;
    const int t  = threadIdx.x;
    const int lj = t & 63;
    const int lw = t >> 6;
    const bool diag = (ti == tj);

#pragma unroll
    for (int m = 0; m < 16; ++m) {
        const int li = lw * 16 + m;
        const int i = ti * 64 + li;
        const int j = tj * 64 + lj;
        float v = 0.0f;
        if (i < j) v = ang[i * (4095 - i) / 2 + (j - i - 1)];
        tile[li][lj] = v;
    }
    __syncthreads();

#pragma unroll
    for (int m = 0; m < 16; ++m) {
        const int li = lw * 16 + m;
        float v;
        if (diag) {
            if (li < lj)      v =  tile[li][lj];
            else if (li > lj) v = -tile[lj][li];
            else              v = 0.0f;
        } else {
            v = tile[li][lj];
        }
        A[(size_t)(ti * 64 + li) * DIM + tj * 64 + lj] = f2bf(v);
    }
    if (!diag) {
#pragma unroll
        for (int m = 0; m < 16; ++m) {
            const int li = lw * 16 + m;
            A[(size_t)(tj * 64 + li) * DIM + ti * 64 + lj] = f2bf(-tile[lj][li]);
        }
    }
}

// ---------------------------------------------------------------------------
// Merged Wt-builder + x-conversion. Blocks [0,512): Wt = I - 2A - A*A^T
// (128x64 tiles, 16:12 MFMA:ds_read, XCD swizzle). Blocks [512, 512+32768):
// fp32->bf16 cvt of x. Dependency-independent; s64 blocks compute-bound,
// cvt blocks memory-bound -> overlap (m114). Neutral-measured vs separate
// launches (R6), kept for the saved launch gap.
// ---------------------------------------------------------------------------
__global__ __launch_bounds__(256) void s64_cvt(
        const unsigned short* __restrict__ A,
        unsigned short* __restrict__ Wt,
        const float* __restrict__ x,
        unsigned short* __restrict__ xbf) {
    __shared__ __align__(16) unsigned short ldsA[128 * 64];  // 16 KB
    __shared__ __align__(16) unsigned short ldsB[64 * 64];   //  8 KB

    if (blockIdx.x >= 512) {
        // fp32 -> bf16, 4 elems/thread
        const int i = ((blockIdx.x - 512) * 256 + threadIdx.x) * 4;
        const float4 v = *(const float4*)(x + i);
        ushort4 o;
        o.x = f2bf(v.x); o.y = f2bf(v.y); o.z = f2bf(v.z); o.w = f2bf(v.w);
        *(ushort4*)(xbf + i) = o;
        return;
    }

    const int K = DIM, N = DIM;
    const int t    = threadIdx.x;
    const int flat = blockIdx.x;                             // 0..511
    const int swz  = (flat & 7) * 64 + (flat >> 3);          // bijective
    const int bn   = (swz & 31) * 64;
    const int bm   = (swz >> 5) * 128;
    const int lane = t & 63;
    const int wave = t >> 6;
    const int waveM = (wave >> 1) * 64;
    const int waveN = (wave & 1) * 32;
    const int fm = lane & 15;
    const int fq = lane >> 4;

    f32x4 acc[4][2];
#pragma unroll
    for (int i = 0; i < 4; ++i)
#pragma unroll
        for (int j = 0; j < 2; ++j)
            acc[i][j] = (f32x4){0.f, 0.f, 0.f, 0.f};

    const int trow   = t >> 3;                  // 0..31
    const int tchunk = (t & 7) ^ (trow & 7);    // swizzled source k-chunk
    const unsigned short* gA = A + (size_t)(bm + trow) * K + tchunk * 8;
    const unsigned short* gB = A + (size_t)(bn + trow) * K + tchunk * 8;
    const size_t rowskip = (size_t)32 * K;
    unsigned short* lA = ldsA + t * 8;
    unsigned short* lB = ldsB + t * 8;

    for (int kt = 0; kt < K; kt += 64) {
        __syncthreads();
        async16(gA + kt,                lA);
        async16(gA + kt +     rowskip,  lA + 2048);
        async16(gA + kt + 2 * rowskip,  lA + 4096);
        async16(gA + kt + 3 * rowskip,  lA + 6144);
        async16(gB + kt,                lB);
        async16(gB + kt +     rowskip,  lB + 2048);
        __syncthreads();

#pragma unroll
        for (int ks = 0; ks < 2; ++ks) {
            short8 af[4], bfv[2];
#pragma unroll
            for (int i = 0; i < 4; ++i) {
                const int rowA = waveM + i * 16 + fm;
                af[i] = *(const short8*)(ldsA + rowA * 64 + (((ks << 2) + fq) ^ (rowA & 7)) * 8);
            }
#pragma unroll
            for (int j = 0; j < 2; ++j) {
                const int rowB = waveN + j * 16 + fm;
                bfv[j] = *(const short8*)(ldsB + rowB * 64 + (((ks << 2) + fq) ^ (rowB & 7)) * 8);
            }
#pragma unroll
            for (int i = 0; i < 4; ++i)
#pragma unroll
                for (int j = 0; j < 2; ++j)
                    acc[i][j] = __builtin_amdgcn_mfma_f32_16x16x32_bf16(
                        af[i], bfv[j], acc[i][j], 0, 0, 0);
        }
    }

#pragma unroll
    for (int i = 0; i < 4; ++i) {
#pragma unroll
        for (int j = 0; j < 2; ++j) {
            const int col = bn + waveN + j * 16 + fm;
#pragma unroll
            for (int r = 0; r < 4; ++r) {
                const int row = bm + waveM + i * 16 + fq * 4 + r;
                const float a = bf2f(A[(size_t)row * N + col]);
                const float w = (row == col ? 1.0f : 0.0f) - 2.0f * a - acc[i][j][r];
                Wt[(size_t)row * N + col] = f2bf(w);
            }
        }
    }
}

// ---------------------------------------------------------------------------
// Main NT GEMM, 256x256 tile, BK=64, balanced 4-phase counted-vmcnt pipeline.
// Proven 16x16x32 version (R4/R5: 120-122 us, MfmaUtil 48,
// SQ_LDS_BANK_CONFLICT 0, FETCH 98.5 MB). The 32x32x16 variant's fragment
// read pattern (row=lane&31, 2 chunk-bases/instr) measured ~4-way LDS
// conflicts (1.26e7/dispatch) -> net -11%; the 16x16 fm/fq pattern
// (row=lane&15, 4 chunk-bases) is conflict-free on HW.
// ---------------------------------------------------------------------------

#define WAITV(N) asm volatile("s_waitcnt vmcnt(" #N ")" ::: "memory")
#define BAR() do { asm volatile("" ::: "memory"); __builtin_amdgcn_s_barrier(); asm volatile("" ::: "memory"); } while (0)

#define STG_A(BUF, R0, KT) async16(gA + (size_t)(R0) * 2048 + (KT), &ldsA[BUF][(R0) * 64 + t * 8])
#define STG_B(BUF, R0, KT) async16(gB + (size_t)(R0) * 2048 + (KT), &ldsB[BUF][(R0) * 64 + t * 8])

// A fragments for i-half IH into af (8x ds_read_b128)
#define READ_A_(BUF, IH) do { \
    _Pragma("unroll") \
    for (int ii = 0; ii < 4; ++ii) { \
        const int row  = waveM + (IH) * 64 + ii * 16 + fm; \
        const int base = row * 64; \
        af[ii][0] = *(const short8*)(&ldsA[BUF][base + ((fq    ) ^ (row & 7)) * 8]); \
        af[ii][1] = *(const short8*)(&ldsA[BUF][base + ((fq + 4) ^ (row & 7)) * 8]); \
    } } while (0)

// B fragments for j-half JH into bfr[JH] (4x ds_read_b128)
#define READ_B_(BUF, JH) do { \
    _Pragma("unroll") \
    for (int jj = 0; jj < 2; ++jj) { \
        const int row  = (JH) * 128 + wn * 32 + jj * 16 + fm; \
        const int base = row * 64; \
        bfr[JH][jj][0] = *(const short8*)(&ldsB[BUF][base + ((fq    ) ^ (row & 7)) * 8]); \
        bfr[JH][jj][1] = *(const short8*)(&ldsB[BUF][base + ((fq + 4) ^ (row & 7)) * 8]); \
    } } while (0)

#define MMAQ(IH, JH) do { \
    __builtin_amdgcn_s_setprio(1); \
    _Pragma("unroll") \
    for (int ks = 0; ks < 2; ++ks) \
    _Pragma("unroll") \
    for (int ii = 0; ii < 4; ++ii) \
    _Pragma("unroll") \
    for (int jj = 0; jj < 2; ++jj) \
        acc[(IH) * 4 + ii][(JH) * 2 + jj] = __builtin_amdgcn_mfma_f32_16x16x32_bf16( \
            af[ii][ks], bfr[JH][jj][ks], acc[(IH) * 4 + ii][(JH) * 2 + jj], 0, 0, 0); \
    __builtin_amdgcn_s_setprio(0); \
} while (0)

// One K-tile. PRE: prefetch tile T+2 (k-elem KTN) into same buffer.
// VN: vmcnt arg at P3 (6 steady; 0 for tile 30). NXT: pre-read tile T+1 frags.
#define TILE(BUF, KTN, PRE, VN, NXT) do { \
    /* P1: quad (0,0) */ \
    BAR(); \
    if (PRE) { STG_A(BUF, 0, KTN); STG_A(BUF, 128, KTN); STG_B(BUF, 0, KTN); STG_B(BUF, 64, KTN); } \
    MMAQ(0, 0); \
    READ_B_(BUF, 1); \
    /* P2: quad (0,1) */ \
    BAR(); \
    if (PRE) { STG_B(BUF, 128, KTN); STG_B(BUF, 192, KTN); } \
    MMAQ(0, 1); \
    READ_A_(BUF, 1); \
    /* P3: quad (1,0) */ \
    WAITV(VN); \
    BAR(); \
    if (PRE) { STG_A(BUF, 64, KTN); STG_A(BUF, 192, KTN); } \
    MMAQ(1, 0); \
    if (NXT) READ_B_((BUF) ^ 1, 0); \
    /* P4: quad (1,1) */ \
    BAR(); \
    MMAQ(1, 1); \
    if (NXT) READ_A_((BUF) ^ 1, 0); \
} while (0)

#define TILE_LAST(BUF) do { \
    BAR(); MMAQ(0, 0); READ_B_(BUF, 1); \
    BAR(); MMAQ(0, 1); READ_A_(BUF, 1); \
    BAR(); MMAQ(1, 0); \
    MMAQ(1, 1); \
} while (0)

__global__ __launch_bounds__(512, 2) void gemm_main(
        const unsigned short* __restrict__ Aop,   // x bf16 [M][K]
        const unsigned short* __restrict__ Bop,   // Wt bf16 [N][K]
        int M, int N, int K,
        const float* __restrict__ bias,
        float* __restrict__ out) {
    __shared__ __align__(16) unsigned short ldsA[2][256 * 64];  // 2 x 32 KB
    __shared__ __align__(16) unsigned short ldsB[2][256 * 64];  // 2 x 32 KB

    const int t    = threadIdx.x;
    // XCD-aware bijective swizzle over the 8x64 grid (512 blocks, 512%8==0).
    const int flat = blockIdx.y * 8 + blockIdx.x;
    const int swz  = (flat & 7) * 64 + (flat >> 3);
    const int bn   = (swz & 7) * 256;
    const int bm   = (swz >> 3) * 256;
    const int lane = t & 63;
    const int wave = t >> 6;        // 0..7
    const int wm   = wave >> 2;     // 0..1
    const int wn   = wave & 3;      // 0..3
    const int waveM = wm * 128;
    const int fm = lane & 15;
    const int fq = lane >> 4;

    f32x4 acc[8][4];
#pragma unroll
    for (int i = 0; i < 8; ++i)
#pragma unroll
        for (int j = 0; j < 4; ++j)
            acc[i][j] = (f32x4){0.f, 0.f, 0.f, 0.f};

    short8 af[4][2];        // A frags, current i-half (single-buffered)
    short8 bfr[2][2][2];    // B frags per j-half (may hold different tiles)

    const int trow   = t >> 3;                  // 0..63
    const int tchunk = (t & 7) ^ (trow & 7);    // pre-swizzled source k-chunk
    const unsigned short* gA = Aop + (size_t)(bm + trow) * 2048 + tchunk * 8;
    const unsigned short* gB = Bop + (size_t)(bn + trow) * 2048 + tchunk * 8;

    // Prologue: stage tile 0 -> buf0 (8 oldest), tile 1 -> buf1.
    STG_A(0, 0, 0);   STG_A(0, 128, 0);  STG_B(0, 0, 0);   STG_B(0, 64, 0);
    STG_B(0, 128, 0); STG_B(0, 192, 0);  STG_A(0, 64, 0);  STG_A(0, 192, 0);
    STG_A(1, 0, 64);  STG_A(1, 128, 64); STG_B(1, 0, 64);  STG_B(1, 64, 64);
    STG_B(1, 128, 64);STG_B(1, 192, 64); STG_A(1, 64, 64); STG_A(1, 192, 64);
    WAITV(8);           // tile 0's 8 retired; tile 1's 8 in flight
    BAR();
    READ_A_(0, 0);      // af   = A0(tile 0)
    READ_B_(0, 0);      // bfr0 = B0(tile 0)

    // Main loop: tiles 0..29, full prefetch of tiles 2..31.
#pragma unroll 1
    for (int it = 0; it < 15; ++it) {
        const int kt = it * 128;
        TILE(0, kt + 128, 1, 6, 1);   // tile 2it,   prefetch 2it+2
        TILE(1, kt + 192, 1, 6, 1);   // tile 2it+1, prefetch 2it+3
    }
    // Tail: tile 30 (wait out tile 31's loads at P3), tile 31.
    TILE(0, 0, 0, 0, 1);
    TILE_LAST(1);

    // Epilogue: acc -> out (+bias). col mapping matches B frag remap.
#pragma unroll
    for (int i = 0; i < 8; ++i) {
        const int row0 = bm + waveM + i * 16 + fq * 4;
#pragma unroll
        for (int j = 0; j < 4; ++j) {
            const int col = bn + (j >> 1) * 128 + wn * 32 + (j & 1) * 16 + fm;
            const float b = bias[col];
#pragma unroll
            for (int r = 0; r < 4; ++r)
                out[(size_t)(row0 + r) * 2048 + col] = acc[i][j][r] + b;
        }
    }
}

extern "C" void kernel_launch(void* const* d_in, const int* in_sizes, int n_in,
                              void* d_out, int out_size, void* d_ws, size_t ws_size,
                              hipStream_t stream) {
    const float* x      = (const float*)d_in[0];   // 4*4096*2048
    const float* angles = (const float*)d_in[1];   // 2096128
    const float* bias   = (const float*)d_in[2];   // 2048
    float* out = (float*)d_out;

    char* ws = (char*)d_ws;
    unsigned short* Abf = (unsigned short*)ws;                      //  8 MB: A bf16
    unsigned short* Wt  = (unsigned short*)(ws + (8u << 20));       //  8 MB: W^T bf16
    unsigned short* xbf = (unsigned short*)(ws + (16u << 20));      // 64 MB: x bf16

    const int M = 4 * 4096;

    // build A (tiny, dependency of s64)
    build_A_tiled<<<528, 256, 0, stream>>>(angles, Abf);

    // Wt = I - 2A - A*A^T (512 blocks) overlapped with x fp32->bf16 (32768)
    s64_cvt<<<512 + 32768, 256, 0, stream>>>(Abf, Wt, x, xbf);

    // out = x @ W + bias via NT against Wt (16384 x 2048 x 2048)
    gemm_main<<<dim3(DIM / 256, M / 256), 512, 0, stream>>>(
        xbf, Wt, M, DIM, DIM, bias, out);
}

// Round 9
// 349.562 us; speedup vs baseline: 1.0866x; 1.0339x over previous
//
#include <hip/hip_runtime.h>
#include <stdint.h>

#define DIM 2048

typedef short short8 __attribute__((ext_vector_type(8)));
typedef float f32x4 __attribute__((ext_vector_type(4)));

__device__ __forceinline__ unsigned short f2bf(float f) {
    union { float f; unsigned int u; } v;
    v.f = f;
    unsigned int r = v.u + 0x7FFFu + ((v.u >> 16) & 1u);  // round-to-nearest-even
    return (unsigned short)(r >> 16);
}
__device__ __forceinline__ float bf2f(unsigned short u) {
    union { unsigned int u; float f; } v;
    v.u = ((unsigned int)u) << 16;
    return v.f;
}

// async global->LDS, 16B per lane. LDS dest must be wave-uniform base + lane*16.
__device__ __forceinline__ void async16(const unsigned short* g, unsigned short* l) {
    __builtin_amdgcn_global_load_lds(
        (__attribute__((address_space(1))) void*)(uintptr_t)g,
        (__attribute__((address_space(3))) void*)(uintptr_t)l,
        16, 0, 0);
}

// Tiled skew-symmetric build: one block per upper-tri 64x64 tile pair.
__global__ __launch_bounds__(256) void build_A_tiled(const float* __restrict__ ang,
                                                     unsigned short* __restrict__ A) {
    __shared__ float tile[64][65];
    int b = blockIdx.x;
    int ti = 0, rem = b;
    while (rem >= 32 - ti) { rem -= 32 - ti; ++ti; }
    const int tj = ti + rem;
    const int t  = threadIdx.x;
    const int lj = t & 63;
    const int lw = t >> 6;
    const bool diag = (ti == tj);

#pragma unroll
    for (int m = 0; m < 16; ++m) {
        const int li = lw * 16 + m;
        const int i = ti * 64 + li;
        const int j = tj * 64 + lj;
        float v = 0.0f;
        if (i < j) v = ang[i * (4095 - i) / 2 + (j - i - 1)];
        tile[li][lj] = v;
    }
    __syncthreads();

#pragma unroll
    for (int m = 0; m < 16; ++m) {
        const int li = lw * 16 + m;
        float v;
        if (diag) {
            if (li < lj)      v =  tile[li][lj];
            else if (li > lj) v = -tile[lj][li];
            else              v = 0.0f;
        } else {
            v = tile[li][lj];
        }
        A[(size_t)(ti * 64 + li) * DIM + tj * 64 + lj] = f2bf(v);
    }
    if (!diag) {
#pragma unroll
        for (int m = 0; m < 16; ++m) {
            const int li = lw * 16 + m;
            A[(size_t)(tj * 64 + li) * DIM + ti * 64 + lj] = f2bf(-tile[lj][li]);
        }
    }
}

// ---------------------------------------------------------------------------
// Symmetric Wt-builder + x-conversion, one launch.
// Blocks [0,528): one block per upper-tri 64x64 tile-pair (ti<=tj).
//   S = A*A^T is symmetric, A antisymmetric =>
//     Wt[m][n] = d(m,n) - 2*A[m][n] - S[m][n]
//     Wt[n][m] = d(m,n) + 2*A[m][n] - S[m][n]
//   -> compute S-tile once, write both orientations (diag tiles double-write
//   identical values). MFMA work x0.52, A staging fetch x0.5 vs full grid.
//   Transposed tile goes through an LDS 64x65 f32 transpose (reusing the
//   24KB staging space after a barrier) so both stores stay coalesced.
// Blocks [528, 528+32768): fp32->bf16 cvt of x (independent; overlaps).
// K-loop = the R0-R4-proven 64x64 staging/read pattern verbatim.
// ---------------------------------------------------------------------------
__global__ __launch_bounds__(256) void s64sym_cvt(
        const unsigned short* __restrict__ A,
        unsigned short* __restrict__ Wt,
        const float* __restrict__ x,
        unsigned short* __restrict__ xbf) {
    __shared__ __align__(16) unsigned short smem[12288];     // 24 KB
    unsigned short* ldsA = smem;                             // 16 KB (64x64 + 64x64? -> 8KB each)
    unsigned short* ldsB = smem + 4096;                      //  8 KB
    float* ldsT = (float*)smem;                              // 64x65 f32 = 16.6 KB (reused)

    if (blockIdx.x >= 528) {
        // fp32 -> bf16, 4 elems/thread
        const int i = ((blockIdx.x - 528) * 256 + threadIdx.x) * 4;
        const float4 v = *(const float4*)(x + i);
        ushort4 o;
        o.x = f2bf(v.x); o.y = f2bf(v.y); o.z = f2bf(v.z); o.w = f2bf(v.w);
        *(ushort4*)(xbf + i) = o;
        return;
    }

    const int K = DIM, N = DIM;
    const int t = threadIdx.x;
    // XCD-aware bijective swizzle (528 % 8 == 0, 528/8 = 66).
    const int swz = (blockIdx.x & 7) * 66 + (blockIdx.x >> 3);
    int ti = 0, rem = swz;
    while (rem >= 32 - ti) { rem -= 32 - ti; ++ti; }
    const int tj = ti + rem;
    const int bm = ti * 64;
    const int bn = tj * 64;

    const int lane = t & 63;
    const int wave = t >> 6;
    const int waveM = (wave >> 1) * 32;
    const int waveN = (wave & 1) * 32;
    const int fm = lane & 15;
    const int fq = lane >> 4;

    f32x4 acc[2][2];
#pragma unroll
    for (int i = 0; i < 2; ++i)
#pragma unroll
        for (int j = 0; j < 2; ++j)
            acc[i][j] = (f32x4){0.f, 0.f, 0.f, 0.f};

    const int trow   = t >> 3;                  // 0..31
    const int tchunk = (t & 7) ^ (trow & 7);    // swizzled source k-chunk
    const unsigned short* gA = A + (size_t)(bm + trow) * K + tchunk * 8;
    const unsigned short* gB = A + (size_t)(bn + trow) * K + tchunk * 8;
    const size_t rowskip = (size_t)32 * K;
    unsigned short* lA = ldsA + t * 8;
    unsigned short* lB = ldsB + t * 8;

    for (int kt = 0; kt < K; kt += 64) {
        __syncthreads();
        async16(gA + kt, lA);
        async16(gA + kt + rowskip, lA + 2048);
        async16(gB + kt, lB);
        async16(gB + kt + rowskip, lB + 2048);
        __syncthreads();

#pragma unroll
        for (int ks = 0; ks < 2; ++ks) {
            short8 af[2], bfv[2];
#pragma unroll
            for (int i = 0; i < 2; ++i) {
                const int rowA = waveM + i * 16 + fm;
                const int rowB = waveN + i * 16 + fm;
                af[i]  = *(const short8*)(ldsA + rowA * 64 + (((ks << 2) + fq) ^ (rowA & 7)) * 8);
                bfv[i] = *(const short8*)(ldsB + rowB * 64 + (((ks << 2) + fq) ^ (rowB & 7)) * 8);
            }
#pragma unroll
            for (int i = 0; i < 2; ++i)
#pragma unroll
                for (int j = 0; j < 2; ++j)
                    acc[i][j] = __builtin_amdgcn_mfma_f32_16x16x32_bf16(
                        af[i], bfv[j], acc[i][j], 0, 0, 0);
        }
    }

    // Epilogue: direct tile (ti,tj) written straight; transposed tile (tj,ti)
    // staged via LDS so its stores are coalesced.
    __syncthreads();   // all staging reads done CU-wide before ldsT overwrite
#pragma unroll
    for (int i = 0; i < 2; ++i) {
#pragma unroll
        for (int j = 0; j < 2; ++j) {
            const int lj = waveN + j * 16 + fm;
            const int gj = bn + lj;
#pragma unroll
            for (int r = 0; r < 4; ++r) {
                const int li = waveM + i * 16 + fq * 4 + r;
                const int gi = bm + li;
                const float a = bf2f(A[(size_t)gi * N + gj]);
                const float s = acc[i][j][r];
                const float d = (gi == gj) ? 1.0f : 0.0f;
                Wt[(size_t)gi * N + gj] = f2bf(d - 2.0f * a - s);
                ldsT[lj * 65 + li] = d + 2.0f * a - s;     // Wt[gj][gi]
            }
        }
    }
    __syncthreads();
    // Transposed store: thread t -> row r=t>>2 of tile (tj,ti), 16 cols.
    {
        const int r  = t >> 2;
        const int cb = (t & 3) * 16;
        unsigned short o[16];
#pragma unroll
        for (int u = 0; u < 16; ++u)
            o[u] = f2bf(ldsT[r * 65 + cb + u]);
        *(short8*)(Wt + (size_t)(bn + r) * N + bm + cb)     = *(short8*)(o);
        *(short8*)(Wt + (size_t)(bn + r) * N + bm + cb + 8) = *(short8*)(o + 8);
    }
}

// ---------------------------------------------------------------------------
// Main NT GEMM, 256x256 tile, BK=64, balanced 4-phase counted-vmcnt pipeline.
// FROZEN: twice-measured at 120-125 us, MfmaUtil 48-50, conflicts 0,
// FETCH 98.5 MB. LDS-pipe arithmetic (8 waves x 24 ds_read_b128 ~ 768+ cyc
// vs 620 cyc MFMA per CU per K-tile) says this structure is near its
// LDS-throughput ceiling; do not perturb without a traffic-reducing redesign.
// ---------------------------------------------------------------------------

#define WAITV(N) asm volatile("s_waitcnt vmcnt(" #N ")" ::: "memory")
#define BAR() do { asm volatile("" ::: "memory"); __builtin_amdgcn_s_barrier(); asm volatile("" ::: "memory"); } while (0)

#define STG_A(BUF, R0, KT) async16(gA + (size_t)(R0) * 2048 + (KT), &ldsA[BUF][(R0) * 64 + t * 8])
#define STG_B(BUF, R0, KT) async16(gB + (size_t)(R0) * 2048 + (KT), &ldsB[BUF][(R0) * 64 + t * 8])

// A fragments for i-half IH into af (8x ds_read_b128)
#define READ_A_(BUF, IH) do { \
    _Pragma("unroll") \
    for (int ii = 0; ii < 4; ++ii) { \
        const int row  = waveM + (IH) * 64 + ii * 16 + fm; \
        const int base = row * 64; \
        af[ii][0] = *(const short8*)(&ldsA[BUF][base + ((fq    ) ^ (row & 7)) * 8]); \
        af[ii][1] = *(const short8*)(&ldsA[BUF][base + ((fq + 4) ^ (row & 7)) * 8]); \
    } } while (0)

// B fragments for j-half JH into bfr[JH] (4x ds_read_b128)
#define READ_B_(BUF, JH) do { \
    _Pragma("unroll") \
    for (int jj = 0; jj < 2; ++jj) { \
        const int row  = (JH) * 128 + wn * 32 + jj * 16 + fm; \
        const int base = row * 64; \
        bfr[JH][jj][0] = *(const short8*)(&ldsB[BUF][base + ((fq    ) ^ (row & 7)) * 8]); \
        bfr[JH][jj][1] = *(const short8*)(&ldsB[BUF][base + ((fq + 4) ^ (row & 7)) * 8]); \
    } } while (0)

#define MMAQ(IH, JH) do { \
    __builtin_amdgcn_s_setprio(1); \
    _Pragma("unroll") \
    for (int ks = 0; ks < 2; ++ks) \
    _Pragma("unroll") \
    for (int ii = 0; ii < 4; ++ii) \
    _Pragma("unroll") \
    for (int jj = 0; jj < 2; ++jj) \
        acc[(IH) * 4 + ii][(JH) * 2 + jj] = __builtin_amdgcn_mfma_f32_16x16x32_bf16( \
            af[ii][ks], bfr[JH][jj][ks], acc[(IH) * 4 + ii][(JH) * 2 + jj], 0, 0, 0); \
    __builtin_amdgcn_s_setprio(0); \
} while (0)

// One K-tile. PRE: prefetch tile T+2 (k-elem KTN) into same buffer.
// VN: vmcnt arg at P3 (6 steady; 0 for tile 30). NXT: pre-read tile T+1 frags.
#define TILE(BUF, KTN, PRE, VN, NXT) do { \
    /* P1: quad (0,0) */ \
    BAR(); \
    if (PRE) { STG_A(BUF, 0, KTN); STG_A(BUF, 128, KTN); STG_B(BUF, 0, KTN); STG_B(BUF, 64, KTN); } \
    MMAQ(0, 0); \
    READ_B_(BUF, 1); \
    /* P2: quad (0,1) */ \
    BAR(); \
    if (PRE) { STG_B(BUF, 128, KTN); STG_B(BUF, 192, KTN); } \
    MMAQ(0, 1); \
    READ_A_(BUF, 1); \
    /* P3: quad (1,0) */ \
    WAITV(VN); \
    BAR(); \
    if (PRE) { STG_A(BUF, 64, KTN); STG_A(BUF, 192, KTN); } \
    MMAQ(1, 0); \
    if (NXT) READ_B_((BUF) ^ 1, 0); \
    /* P4: quad (1,1) */ \
    BAR(); \
    MMAQ(1, 1); \
    if (NXT) READ_A_((BUF) ^ 1, 0); \
} while (0)

#define TILE_LAST(BUF) do { \
    BAR(); MMAQ(0, 0); READ_B_(BUF, 1); \
    BAR(); MMAQ(0, 1); READ_A_(BUF, 1); \
    BAR(); MMAQ(1, 0); \
    MMAQ(1, 1); \
} while (0)

__global__ __launch_bounds__(512, 2) void gemm_main(
        const unsigned short* __restrict__ Aop,   // x bf16 [M][K]
        const unsigned short* __restrict__ Bop,   // Wt bf16 [N][K]
        int M, int N, int K,
        const float* __restrict__ bias,
        float* __restrict__ out) {
    __shared__ __align__(16) unsigned short ldsA[2][256 * 64];  // 2 x 32 KB
    __shared__ __align__(16) unsigned short ldsB[2][256 * 64];  // 2 x 32 KB

    const int t    = threadIdx.x;
    // XCD-aware bijective swizzle over the 8x64 grid (512 blocks, 512%8==0).
    const int flat = blockIdx.y * 8 + blockIdx.x;
    const int swz  = (flat & 7) * 64 + (flat >> 3);
    const int bn   = (swz & 7) * 256;
    const int bm   = (swz >> 3) * 256;
    const int lane = t & 63;
    const int wave = t >> 6;        // 0..7
    const int wm   = wave >> 2;     // 0..1
    const int wn   = wave & 3;      // 0..3
    const int waveM = wm * 128;
    const int fm = lane & 15;
    const int fq = lane >> 4;

    f32x4 acc[8][4];
#pragma unroll
    for (int i = 0; i < 8; ++i)
#pragma unroll
        for (int j = 0; j < 4; ++j)
            acc[i][j] = (f32x4){0.f, 0.f, 0.f, 0.f};

    short8 af[4][2];        // A frags, current i-half (single-buffered)
    short8 bfr[2][2][2];    // B frags per j-half (may hold different tiles)

    const int trow   = t >> 3;                  // 0..63
    const int tchunk = (t & 7) ^ (trow & 7);    // pre-swizzled source k-chunk
    const unsigned short* gA = Aop + (size_t)(bm + trow) * 2048 + tchunk * 8;
    const unsigned short* gB = Bop + (size_t)(bn + trow) * 2048 + tchunk * 8;

    // Prologue: stage tile 0 -> buf0 (8 oldest), tile 1 -> buf1.
    STG_A(0, 0, 0);   STG_A(0, 128, 0);  STG_B(0, 0, 0);   STG_B(0, 64, 0);
    STG_B(0, 128, 0); STG_B(0, 192, 0);  STG_A(0, 64, 0);  STG_A(0, 192, 0);
    STG_A(1, 0, 64);  STG_A(1, 128, 64); STG_B(1, 0, 64);  STG_B(1, 64, 64);
    STG_B(1, 128, 64);STG_B(1, 192, 64); STG_A(1, 64, 64); STG_A(1, 192, 64);
    WAITV(8);           // tile 0's 8 retired; tile 1's 8 in flight
    BAR();
    READ_A_(0, 0);      // af   = A0(tile 0)
    READ_B_(0, 0);      // bfr0 = B0(tile 0)

    // Main loop: tiles 0..29, full prefetch of tiles 2..31.
#pragma unroll 1
    for (int it = 0; it < 15; ++it) {
        const int kt = it * 128;
        TILE(0, kt + 128, 1, 6, 1);   // tile 2it,   prefetch 2it+2
        TILE(1, kt + 192, 1, 6, 1);   // tile 2it+1, prefetch 2it+3
    }
    // Tail: tile 30 (wait out tile 31's loads at P3), tile 31.
    TILE(0, 0, 0, 0, 1);
    TILE_LAST(1);

    // Epilogue: acc -> out (+bias). col mapping matches B frag remap.
#pragma unroll
    for (int i = 0; i < 8; ++i) {
        const int row0 = bm + waveM + i * 16 + fq * 4;
#pragma unroll
        for (int j = 0; j < 4; ++j) {
            const int col = bn + (j >> 1) * 128 + wn * 32 + (j & 1) * 16 + fm;
            const float b = bias[col];
#pragma unroll
            for (int r = 0; r < 4; ++r)
                out[(size_t)(row0 + r) * 2048 + col] = acc[i][j][r] + b;
        }
    }
}

extern "C" void kernel_launch(void* const* d_in, const int* in_sizes, int n_in,
                              void* d_out, int out_size, void* d_ws, size_t ws_size,
                              hipStream_t stream) {
    const float* x      = (const float*)d_in[0];   // 4*4096*2048
    const float* angles = (const float*)d_in[1];   // 2096128
    const float* bias   = (const float*)d_in[2];   // 2048
    float* out = (float*)d_out;

    char* ws = (char*)d_ws;
    unsigned short* Abf = (unsigned short*)ws;                      //  8 MB: A bf16
    unsigned short* Wt  = (unsigned short*)(ws + (8u << 20));       //  8 MB: W^T bf16
    unsigned short* xbf = (unsigned short*)(ws + (16u << 20));      // 64 MB: x bf16

    const int M = 4 * 4096;

    // build A (tiny, dependency of s64)
    build_A_tiled<<<528, 256, 0, stream>>>(angles, Abf);

    // Wt via symmetry (528 upper-tri tile-pairs) overlapped with x cvt (32768)
    s64sym_cvt<<<528 + 32768, 256, 0, stream>>>(Abf, Wt, x, xbf);

    // out = x @ W + bias via NT against Wt (16384 x 2048 x 2048)
    gemm_main<<<dim3(DIM / 256, M / 256), 512, 0, stream>>>(
        xbf, Wt, M, DIM, DIM, bias, out);
}